// Round 8
// baseline (164.898 us; speedup 1.0000x reference)
//
#include <hip/hip_runtime.h>
#include <cmath>

typedef _Float16 half8 __attribute__((ext_vector_type(8)));
typedef _Float16 half2v __attribute__((ext_vector_type(2)));
typedef float f32x4 __attribute__((ext_vector_type(4)));
typedef float f32x2 __attribute__((ext_vector_type(2)));

#define B_ 2
#define L_ 2048
#define H_ 8
#define D_ 64
#define S_ 2
#define F_ 5
#define LUTN 2048
#define LSCALE 1448.1547f          // LUTN / sqrt(2)
#define LOG2E 1.44269504f
#define QSC (0.125f * LOG2E)       // folded into Q at preprocess

// ws layout: Q tiles (64x64 f16, swizzled), K tiles (32x64 f16, swizzled),
// VT tiles (superrow-swizzled f16), pre-scaled ks_s coords (f32),
// per-head bias LUT (f32, L1-resident when gathered).
#define QOFF 0            // halfs
#define KOFF 2097152      // halfs
#define VOFF 4194304      // halfs
#define SOFFH 6291456     // halfs -> (float*)(wsh + SOFFH); 32768 B of coords
#define LUTB 12615680     // bytes: 8 heads x 2052 f32 = 65664 B
#define LUTSTRIDE 2052
#define WS_NEED 12681344  // bytes

// main-kernel LDS arena offsets (bytes)
#define OFF_K 0            // 4 groups x 4096 (Q tile overlays groups 0-1 pre-loop)
#define OFF_V 16384        // 4 groups x 4096
#define OFF_P 32768        // 16 waves x 1280  (16 rows x 40 halfs)
#define OFF_KSS 53248      // 4 groups x 256 B (32 keys x f32x2)
#define ARENA_SZ 54272
#define SLOTF (16 * 68 + 16)   // combine slot: O[16][68] f32 + l[16]

#define GLOBAL_LOAD_LDS16(g, l)                                                  \
  __builtin_amdgcn_global_load_lds((const __attribute__((address_space(1))) void*)(g), \
                                   (__attribute__((address_space(3))) void*)(l), 16, 0, 0)

// raw v_sqrt_f32 (1 ULP) — sqrtf() without fast-math emits the IEEE fixup
// sequence (~10 VALU ops); result only feeds a 2048-bin LUT quantizer.
#define FAST_SQRT(x) __builtin_amdgcn_sqrtf(x)

// ---------------- preprocessing: f32 -> f16 swizzled tiles in ws ----------------
// grid 512 = (b,h,u), u in [0,32): Q-tile u (64 rows), K/V tiles 2u, 2u+1 (32 rows).
// Blocks 0..7 additionally build the per-head bias LUT in ws.
__global__ __launch_bounds__(256, 4)
void tisa_preproc(const float* __restrict__ qs, const float* __restrict__ ks,
                  const float* __restrict__ vs, const float* __restrict__ ks_s,
                  const float* __restrict__ ap, const float* __restrict__ bp,
                  const float* __restrict__ cp, _Float16* __restrict__ wsh) {
  __shared__ _Float16 Vl[64 * 72];
  const int t = threadIdx.x;
  const int u = blockIdx.x & 31;
  const int bh = blockIdx.x >> 5;
  const size_t base = ((size_t)(bh >> 3) * L_ + (size_t)u * 64) * (H_ * D_) + (size_t)(bh & 7) * D_;

  // ---- per-head LUT (blocks 0..7): ((bias(d)-8)*log2e) at d=(i+0.5)/LSCALE ----
  if (blockIdx.x < 8) {
    const int hh = blockIdx.x;
    float af[F_], nb[F_], cf[F_];
#pragma unroll
    for (int f = 0; f < F_; ++f) {
      af[f] = ap[hh * F_ + f];
      nb[f] = -fabsf(bp[hh * F_ + f]);
      cf[f] = cp[hh * F_ + f];
    }
    float* lutg = (float*)((char*)wsh + LUTB) + hh * LUTSTRIDE;
    for (int i = t; i <= LUTN; i += 256) {
      float d = ((float)i + 0.5f) * (1.0f / LSCALE);
      float s = 0.f;
#pragma unroll
      for (int f = 0; f < F_; ++f) {
        float e = d - cf[f];
        s += af[f] * __expf(nb[f] * (e * e));
      }
      lutg[i] = (s - 8.0f) * LOG2E;
    }
  }

  // ---- Q: 512 chunks of 8 f32 -> 8 f16, swizzled chunk c^(row&7), scaled by QSC ----
#pragma unroll
  for (int jj = 0; jj < 2; ++jj) {
    int id = t * 2 + jj;              // 0..511
    int row = id >> 3, c = id & 7;
    const float* src = qs + base + (size_t)row * 512 + c * 8;
    f32x4 x0 = ((const f32x4*)src)[0], x1 = ((const f32x4*)src)[1];
    half8 hh;
#pragma unroll
    for (int k = 0; k < 4; ++k) { hh[k] = (_Float16)(x0[k] * QSC); hh[k + 4] = (_Float16)(x1[k] * QSC); }
    *(half8*)&wsh[QOFF + ((size_t)bh * 32 + u) * 4096 + row * 64 + (c ^ (row & 7)) * 8] = hh;
  }
  // ---- K: two 32-row tiles, same chunk swizzle ----
#pragma unroll
  for (int jj = 0; jj < 2; ++jj) {
    int id = t * 2 + jj;
    int tile = id >> 8, row = (id >> 3) & 31, c = id & 7;
    const float* src = ks + base + (size_t)(tile * 32 + row) * 512 + c * 8;
    f32x4 x0 = ((const f32x4*)src)[0], x1 = ((const f32x4*)src)[1];
    half8 hh;
#pragma unroll
    for (int k = 0; k < 4; ++k) { hh[k] = (_Float16)x0[k]; hh[k + 4] = (_Float16)x1[k]; }
    *(half8*)&wsh[KOFF + ((size_t)bh * 64 + u * 2 + tile) * 2048 + row * 64 + (c ^ (row & 7)) * 8] = hh;
  }
  // ---- scaled ks_s coords (h==0 blocks only; 64 keys = 128 floats) ----
  if ((bh & 7) == 0 && t < 32) {
    const int b = bh >> 3;
    const float* src = ks_s + ((size_t)b * L_ + u * 64) * 2 + t * 4;
    float* dst = (float*)(wsh + SOFFH) + ((size_t)b * L_ + u * 64) * 2 + t * 4;
    f32x4 x = *(const f32x4*)src;
    x *= LSCALE;
    *(f32x4*)dst = x;
  }
  // ---- V: stage f16 in LDS, then transposed superrow-swizzled tiles ----
  {
    int key = t >> 2, d0 = (t & 3) * 16;
    const float* src = vs + base + (size_t)key * 512 + d0;
    f32x4 a0 = ((const f32x4*)src)[0], a1 = ((const f32x4*)src)[1];
    f32x4 a2 = ((const f32x4*)src)[2], a3 = ((const f32x4*)src)[3];
    half8 h0, h1;
#pragma unroll
    for (int k = 0; k < 4; ++k) {
      h0[k] = (_Float16)a0[k]; h0[k + 4] = (_Float16)a1[k];
      h1[k] = (_Float16)a2[k]; h1[k + 4] = (_Float16)a3[k];
    }
    *(half8*)&Vl[key * 72 + d0] = h0;
    *(half8*)&Vl[key * 72 + d0 + 8] = h1;
  }
  __syncthreads();
  // superrow s holds d=2s,2s+1; slot c' = (d&1)*4 + (k>>3); stored at c'^(s&7)
#pragma unroll
  for (int jj = 0; jj < 2; ++jj) {
    int id = t * 2 + jj;
    int tile = id >> 8, s = (id >> 3) & 31, cp2 = id & 7;
    int d = 2 * s + (cp2 >> 2), kb = (cp2 & 3) * 8;
    half8 hh;
#pragma unroll
    for (int j = 0; j < 8; ++j) hh[j] = Vl[(tile * 32 + kb + j) * 72 + d];
    *(half8*)&wsh[VOFF + ((size_t)bh * 64 + u * 2 + tile) * 2048 + s * 64 + (cp2 ^ (s & 7)) * 8] = hh;
  }
}

// ---------------- main kernel: 1024 thr = 4 q-slices x 4 K-quarters ----------------
__global__ __launch_bounds__(1024, 8)
void tisa_attn_main(const float* __restrict__ qs_s, const _Float16* __restrict__ wsh,
                    float* __restrict__ out) {
  __shared__ __align__(16) char arena[ARENA_SZ];

  const int t = threadIdx.x;
  const int lane = t & 63;
  const int w = t >> 6;       // 0..15
  const int g = w >> 2;       // K-quarter 0..3
  const int qw = w & 3;       // q-slice 0..3
  const int t2 = t & 255;     // index within group
  const int quad = lane >> 4;
  const int l16 = lane & 15;

  const int qt = blockIdx.x & 31;
  const int bh = blockIdx.x >> 5;
  const int h = bh & 7;
  const int b = bh >> 3;
  const int q0 = qt * 64;

  // per-head LUT base in ws (L1-resident; gathered via VMEM, not LDS)
  const float* LUTg = (const float*)((const char*)wsh + LUTB) + h * LUTSTRIDE;

  // q coords (pre-scaled by LSCALE) for rows qw*16 + quad*4 + r
  float qx[4], qy[4];
#pragma unroll
  for (int r = 0; r < 4; ++r) {
    int qrow = q0 + qw * 16 + quad * 4 + r;
    qx[r] = qs_s[((size_t)b * L_ + qrow) * 2 + 0] * LSCALE;
    qy[r] = qs_s[((size_t)b * L_ + qrow) * 2 + 1] * LSCALE;
  }

  const _Float16* Qt = wsh + QOFF + ((size_t)bh * 32 + qt) * 4096;
  const _Float16* Kbh = wsh + KOFF + (size_t)bh * 64 * 2048;
  const _Float16* Vbh = wsh + VOFF + (size_t)bh * 64 * 2048;
  const float* wsS = (const float*)(wsh + SOFFH);

  // ---- Q tile (8 KB) -> arena[OFF_K..], waves 0..7 ----
  if (w < 8)
    GLOBAL_LOAD_LDS16(Qt + w * 512 + lane * 8, arena + OFF_K + w * 1024);
  __syncthreads();  // Q staged

  half8 qA[2];
#pragma unroll
  for (int kb = 0; kb < 2; ++kb)
    qA[kb] = *(const half8*)(arena + OFF_K + (qw * 16 + l16) * 128 +
                             ((kb * 4 + quad) ^ (l16 & 7)) * 16);

  f32x4 oc[4];
#pragma unroll
  for (int df = 0; df < 4; ++df) oc[df] = (f32x4){0.f, 0.f, 0.f, 0.f};
  f32x4 lsacc = (f32x4){0.f, 0.f, 0.f, 0.f};
  half8 onesv;
#pragma unroll
  for (int j = 0; j < 8; ++j) onesv[j] = (_Float16)1.0f;

  const _Float16* ksrc = Kbh + (size_t)(g * 16) * 2048 + t2 * 8;
  const _Float16* vsrc = Vbh + (size_t)(g * 16) * 2048 + t2 * 8;
  const f32x2* ssrc = (const f32x2*)(wsS + ((size_t)b * L_ + g * 512) * 2);  // pre-scaled coords
  char* kdst = arena + OFF_K + g * 4096 + qw * 1024;   // wave-uniform
  char* vdst = arena + OFF_V + g * 4096 + qw * 1024;
  f32x2* kssG = (f32x2*)(arena + OFF_KSS + g * 256);
  _Float16* Pw = (_Float16*)(arena + OFF_P + w * 1280 + quad * 320 + l16 * 2);

  for (int it = 0; it < 16; ++it) {
    __syncthreads();  // prev iter's frag reads done (iter 0: qA reads done)
    GLOBAL_LOAD_LDS16(ksrc, kdst);
    GLOBAL_LOAD_LDS16(vsrc, vdst);
    ksrc += 2048; vsrc += 2048;
    if (t2 < 32) kssG[t2] = ssrc[t2];   // plain copy (coords pre-scaled in ws)
    ssrc += 32;
    __syncthreads();  // tiles + coords visible (barrier drains vmcnt/lgkmcnt)

    // ---- QK^T: 4 MFMA ----
    f32x4 acc[2];
#pragma unroll
    for (int nf = 0; nf < 2; ++nf) {
      f32x4 a = (f32x4){0.f, 0.f, 0.f, 0.f};
#pragma unroll
      for (int kb = 0; kb < 2; ++kb) {
        half8 kf = *(const half8*)(arena + OFF_K + g * 4096 + (nf * 16 + l16) * 128 +
                                   ((kb * 4 + quad) ^ (l16 & 7)) * 16);
        a = __builtin_amdgcn_mfma_f32_16x16x32_f16(qA[kb], kf, a, 0, 0, 0);
      }
      acc[nf] = a;
    }

    // ---- scores: dist -> global-LUT gather (VMEM) -> exp2; P f16 scatter ----
#pragma unroll
    for (int nf = 0; nf < 2; ++nf) {
      f32x2 kc = kssG[nf * 16 + l16];
#pragma unroll
      for (int r = 0; r < 4; ++r) {
        float dx = qx[r] - kc.x, dy = qy[r] - kc.y;
        float tt = FAST_SQRT(fmaf(dx, dx, dy * dy));   // = dist * LSCALE
        int ii = (int)tt;
        float p = __builtin_amdgcn_exp2f(acc[nf][r] + LUTg[ii]);
        acc[nf][r] = p;
        Pw[r * 40 + nf * 16] = (_Float16)p;   // P[qrow=quad*4+r][key=nf*16+l16]
      }
    }

    // ---- PV + row-sum via ones-MFMA; same-wave DS ordering, no barrier ----
    half8 pa = *(const half8*)(arena + OFF_P + w * 1280 + l16 * 80 + quad * 16);
    lsacc = __builtin_amdgcn_mfma_f32_16x16x32_f16(pa, onesv, lsacc, 0, 0, 0);
#pragma unroll
    for (int df = 0; df < 4; ++df) {
      half8 vf = *(const half8*)(arena + OFF_V + g * 4096 + (l16 >> 1) * 128 + df * 1024 +
                                 ((((l16 & 1) * 4 + quad) ^ ((l16 >> 1) & 7)) * 16));
      oc[df] = __builtin_amdgcn_mfma_f32_16x16x32_f16(pa, vf, oc[df], 0, 0, 0);
    }
  }

  // ---- combine 4 K-quarters via LDS tree (row sums already reduced by ones-MFMA) ----
  float lred[4];
#pragma unroll
  for (int r = 0; r < 4; ++r) lred[r] = lsacc[r];
  __syncthreads();  // all loop LDS reads done; arena reusable
  float* slots = (float*)arena;
  if (g >= 2) {
    float* sl = slots + ((g - 2) * 4 + qw) * SLOTF;
#pragma unroll
    for (int df = 0; df < 4; ++df)
#pragma unroll
      for (int r = 0; r < 4; ++r)
        sl[(quad * 4 + r) * 68 + df * 16 + l16] = oc[df][r];
    if (l16 == 0) {
#pragma unroll
      for (int r = 0; r < 4; ++r) sl[16 * 68 + quad * 4 + r] = lred[r];
    }
  }
  __syncthreads();
  if (g < 2) {
    float* sl = slots + (g * 4 + qw) * SLOTF;   // g0<-slot(g2), g1<-slot(g3)
#pragma unroll
    for (int df = 0; df < 4; ++df)
#pragma unroll
      for (int r = 0; r < 4; ++r)
        oc[df][r] += sl[(quad * 4 + r) * 68 + df * 16 + l16];
#pragma unroll
    for (int r = 0; r < 4; ++r) lred[r] += sl[16 * 68 + quad * 4 + r];
  }
  if (g == 1) {  // write combined back into same slot (same-wave, in-order)
    float* sl = slots + (4 + qw) * SLOTF;
#pragma unroll
    for (int df = 0; df < 4; ++df)
#pragma unroll
      for (int r = 0; r < 4; ++r)
        sl[(quad * 4 + r) * 68 + df * 16 + l16] = oc[df][r];
    if (l16 == 0) {
#pragma unroll
      for (int r = 0; r < 4; ++r) sl[16 * 68 + quad * 4 + r] = lred[r];
    }
  }
  __syncthreads();
  if (g == 0) {
    float* sl = slots + (4 + qw) * SLOTF;
    float inv_l[4];
#pragma unroll
    for (int r = 0; r < 4; ++r)
      inv_l[r] = 1.f / (lred[r] + sl[16 * 68 + quad * 4 + r]);
#pragma unroll
    for (int df = 0; df < 4; ++df)
#pragma unroll
      for (int r = 0; r < 4; ++r) {
        int qrow = q0 + qw * 16 + quad * 4 + r;
        float v = oc[df][r] + sl[(quad * 4 + r) * 68 + df * 16 + l16];
        out[((size_t)(b * L_ + qrow)) * (H_ * D_) + h * D_ + df * 16 + l16] = v * inv_l[r];
      }
  }
}

// ---------------- fallback (R3 kernel) if ws too small ----------------
#define KSTR 72
#define PH 72
#define FLUTN 512
#define FLSCALE 362.03867f
__global__ __launch_bounds__(512, 4)
void tisa_attn_fallback(const float* __restrict__ qs, const float* __restrict__ ks,
                        const float* __restrict__ vs, const float* __restrict__ qs_s,
                        const float* __restrict__ ks_s, const float* __restrict__ ap,
                        const float* __restrict__ bp, const float* __restrict__ cp,
                        float* __restrict__ out) {
  __shared__ _Float16 Ks[2][64 * KSTR];
  __shared__ _Float16 VT[2][D_ * KSTR];
  __shared__ _Float16 Pf[8][16 * PH];
  __shared__ float kss2[2][64 * 2];
  __shared__ f32x2 LUT2s[FLUTN + 1];
  __shared__ float comb[4][16][64];
  __shared__ float combl[4][16];

  const int t = threadIdx.x;
  const int lane = t & 63;
  const int w = t >> 6;
  const int g = w >> 2;
  const int qw = w & 3;
  const int t2 = t & 255;
  const int quad = lane >> 4;
  const int l16 = lane & 15;
  const int qt = blockIdx.x & 31;
  const int bh = blockIdx.x >> 5;
  const int h = bh & 7;
  const int b = bh >> 3;
  const int q0 = qt * 64;

  float af[F_], nb[F_], cf[F_];
#pragma unroll
  for (int f = 0; f < F_; ++f) {
    af[f] = ap[h * F_ + f];
    nb[f] = -fabsf(bp[h * F_ + f]);
    cf[f] = cp[h * F_ + f];
  }
  for (int i = t; i <= FLUTN; i += 512) {
    float d0 = (float)i * (1.0f / FLSCALE), d1 = (float)(i + 1) * (1.0f / FLSCALE);
    float s0 = 0.f, s1 = 0.f;
#pragma unroll
    for (int f = 0; f < F_; ++f) {
      float e0 = d0 - cf[f], e1 = d1 - cf[f];
      s0 += af[f] * __expf(nb[f] * (e0 * e0));
      s1 += af[f] * __expf(nb[f] * (e1 * e1));
    }
    LUT2s[i] = (f32x2){s0 - 8.0f, s1 - 8.0f};
  }
  float qx[4], qy[4];
#pragma unroll
  for (int r = 0; r < 4; ++r) {
    int qrow = q0 + qw * 16 + quad * 4 + r;
    qx[r] = qs_s[(b * L_ + qrow) * S_ + 0];
    qy[r] = qs_s[(b * L_ + qrow) * S_ + 1];
  }
  if (t < 256) {
    const int row = t >> 2, dc = (t & 3) * 16;
    const float* src = qs + (((size_t)(b * L_ + q0 + row)) * H_ + h) * D_ + dc;
    const f32x4* s4 = (const f32x4*)src;
    f32x4 v0 = s4[0], v1 = s4[1], v2 = s4[2], v3 = s4[3];
    half8 w0, w1;
#pragma unroll
    for (int u = 0; u < 4; ++u) {
      w0[u] = (_Float16)(v0[u] * 0.125f); w0[u + 4] = (_Float16)(v1[u] * 0.125f);
      w1[u] = (_Float16)(v2[u] * 0.125f); w1[u + 4] = (_Float16)(v3[u] * 0.125f);
    }
    *(half8*)&Ks[0][row * KSTR + dc] = w0;
    *(half8*)&Ks[0][row * KSTR + dc + 8] = w1;
  }
  __syncthreads();
  half8 qA[2];
#pragma unroll
  for (int kb = 0; kb < 2; ++kb)
    qA[kb] = *(const half8*)&Ks[0][(qw * 16 + l16) * KSTR + kb * 32 + quad * 8];
  f32x4 oc[4];
#pragma unroll
  for (int df = 0; df < 4; ++df) oc[df] = (f32x4){0.f, 0.f, 0.f, 0.f};
  float l_r[4] = {0.f, 0.f, 0.f, 0.f};

  for (int it = 0; it < 16; ++it) {
    const int k0 = (g * 16 + it) * 64;
    __syncthreads();
    {
      const int row = t2 >> 2, dc = (t2 & 3) * 16;
      const float* src = ks + (((size_t)(b * L_ + k0 + row)) * H_ + h) * D_ + dc;
      const f32x4* s4 = (const f32x4*)src;
      f32x4 v0 = s4[0], v1 = s4[1], v2 = s4[2], v3 = s4[3];
      half8 w0, w1;
#pragma unroll
      for (int u = 0; u < 4; ++u) {
        w0[u] = (_Float16)v0[u]; w0[u + 4] = (_Float16)v1[u];
        w1[u] = (_Float16)v2[u]; w1[u + 4] = (_Float16)v3[u];
      }
      *(half8*)&Ks[g][row * KSTR + dc] = w0;
      *(half8*)&Ks[g][row * KSTR + dc + 8] = w1;
    }
    {
      const int kk = (t2 & 31) * 2, dg = (t2 >> 5) * 8;
      const float* s0 = vs + (((size_t)(b * L_ + k0 + kk)) * H_ + h) * D_ + dg;
      const float* s1 = s0 + H_ * D_;
      f32x4 a0 = ((const f32x4*)s0)[0], a1 = ((const f32x4*)s0)[1];
      f32x4 b0 = ((const f32x4*)s1)[0], b1 = ((const f32x4*)s1)[1];
#pragma unroll
      for (int u = 0; u < 4; ++u) {
        half2v p0 = {(_Float16)a0[u], (_Float16)b0[u]};
        *(half2v*)&VT[g][(dg + u) * KSTR + kk] = p0;
        half2v p1 = {(_Float16)a1[u], (_Float16)b1[u]};
        *(half2v*)&VT[g][(dg + 4 + u) * KSTR + kk] = p1;
      }
    }
    if (t2 < 128) kss2[g][t2] = ks_s[((size_t)(b * L_) + k0 + (t2 >> 1)) * S_ + (t2 & 1)];
    __syncthreads();
    f32x4 acc[4];
#pragma unroll
    for (int nf = 0; nf < 4; ++nf) {
      f32x4 a = (f32x4){0.f, 0.f, 0.f, 0.f};
#pragma unroll
      for (int kb = 0; kb < 2; ++kb) {
        half8 kf = *(const half8*)&Ks[g][(nf * 16 + l16) * KSTR + kb * 32 + quad * 8];
        a = __builtin_amdgcn_mfma_f32_16x16x32_f16(qA[kb], kf, a, 0, 0, 0);
      }
      acc[nf] = a;
    }
#pragma unroll
    for (int nf = 0; nf < 4; ++nf) {
      float kx = kss2[g][(nf * 16 + l16) * 2 + 0];
      float ky = kss2[g][(nf * 16 + l16) * 2 + 1];
#pragma unroll
      for (int r = 0; r < 4; ++r) {
        float dx = qx[r] - kx, dy = qy[r] - ky;
        float dist = FAST_SQRT(fmaf(dx, dx, dy * dy));
        float tt = dist * FLSCALE;
        int ii = (int)tt;
        float fr = tt - (float)ii;
        f32x2 lh = LUT2s[ii];
        float p = __expf(acc[nf][r] + fmaf(fr, lh.y - lh.x, lh.x));
        acc[nf][r] = p;
      }
    }
#pragma unroll
    for (int r = 0; r < 4; ++r)
      l_r[r] += (acc[0][r] + acc[1][r]) + (acc[2][r] + acc[3][r]);
#pragma unroll
    for (int nf = 0; nf < 4; ++nf)
#pragma unroll
      for (int r = 0; r < 4; ++r)
        Pf[w][(quad * 4 + r) * PH + nf * 16 + l16] = (_Float16)acc[nf][r];
#pragma unroll
    for (int kb = 0; kb < 2; ++kb) {
      half8 pa = *(const half8*)&Pf[w][l16 * PH + kb * 32 + quad * 8];
#pragma unroll
      for (int df = 0; df < 4; ++df) {
        half8 vf = *(const half8*)&VT[g][(df * 16 + l16) * KSTR + kb * 32 + quad * 8];
        oc[df] = __builtin_amdgcn_mfma_f32_16x16x32_f16(pa, vf, oc[df], 0, 0, 0);
      }
    }
  }
  __syncthreads();
  float lred[4];
#pragma unroll
  for (int r = 0; r < 4; ++r) {
    float s = l_r[r];
    s += __shfl_xor(s, 1); s += __shfl_xor(s, 2);
    s += __shfl_xor(s, 4); s += __shfl_xor(s, 8);
    lred[r] = s;
  }
  if (g == 1) {
#pragma unroll
    for (int df = 0; df < 4; ++df)
#pragma unroll
      for (int r = 0; r < 4; ++r)
        comb[qw][quad * 4 + r][df * 16 + l16] = oc[df][r];
    if (l16 == 0) {
#pragma unroll
      for (int r = 0; r < 4; ++r) combl[qw][quad * 4 + r] = lred[r];
    }
  }
  __syncthreads();
  if (g == 0) {
    float inv_l[4];
#pragma unroll
    for (int r = 0; r < 4; ++r)
      inv_l[r] = 1.f / (lred[r] + combl[qw][quad * 4 + r]);
#pragma unroll
    for (int df = 0; df < 4; ++df)
#pragma unroll
      for (int r = 0; r < 4; ++r) {
        int qrow = q0 + qw * 16 + quad * 4 + r;
        float v = oc[df][r] + comb[qw][quad * 4 + r][df * 16 + l16];
        out[(((size_t)(b * L_ + qrow)) * H_ + h) * D_ + df * 16 + l16] = v * inv_l[r];
      }
  }
}

extern "C" void kernel_launch(void* const* d_in, const int* in_sizes, int n_in,
                              void* d_out, int out_size, void* d_ws, size_t ws_size,
                              hipStream_t stream) {
  const float* qs = (const float*)d_in[0];
  const float* ks = (const float*)d_in[1];
  const float* vs = (const float*)d_in[2];
  const float* qs_s = (const float*)d_in[3];
  const float* ks_s = (const float*)d_in[4];
  const float* ap = (const float*)d_in[5];
  const float* bp = (const float*)d_in[6];
  const float* cp = (const float*)d_in[7];
  float* out = (float*)d_out;

  if (ws_size >= (size_t)WS_NEED) {
    _Float16* wsh = (_Float16*)d_ws;
    tisa_preproc<<<dim3(512), dim3(256), 0, stream>>>(qs, ks, vs, ks_s, ap, bp, cp, wsh);
    tisa_attn_main<<<dim3(512), dim3(1024), 0, stream>>>(qs_s, wsh, out);
  } else {
    tisa_attn_fallback<<<dim3(512), dim3(512), 0, stream>>>(qs, ks, vs, qs_s, ks_s, ap, bp, cp, out);
  }
}

// Round 9
// 154.377 us; speedup vs baseline: 1.0682x; 1.0682x over previous
//
#include <hip/hip_runtime.h>
#include <cmath>

typedef _Float16 half8 __attribute__((ext_vector_type(8)));
typedef _Float16 half4 __attribute__((ext_vector_type(4)));
typedef _Float16 half2v __attribute__((ext_vector_type(2)));
typedef float f32x4 __attribute__((ext_vector_type(4)));
typedef float f32x2 __attribute__((ext_vector_type(2)));

#define B_ 2
#define L_ 2048
#define H_ 8
#define D_ 64
#define S_ 2
#define F_ 5
#define LUTN 2048
#define LSCALE 1448.1547f          // LUTN / sqrt(2)
#define LOG2E 1.44269504f
#define QSC (0.125f * LOG2E)       // folded into Q at preprocess

// ws layout: Q tiles (64x64 f16, swizzled), K tiles (32x64 f16, swizzled),
// VT tiles (superrow-swizzled f16), then pre-scaled ks_s coords (f32).
#define QOFF 0            // halfs
#define KOFF 2097152      // halfs
#define VOFF 4194304      // halfs
#define SOFFH 6291456     // halfs -> (float*)(wsh + SOFFH)
#define WS_NEED 12615680  // bytes

// main-kernel LDS arena offsets (bytes)
#define OFF_K 0            // 4 groups x 4096 (Q tile overlays groups 0-1 pre-loop)
#define OFF_V 16384        // 4 groups x 4096
#define OFF_P 32768        // 16 waves x 1280  (16 q-rows x 40 halfs, key-major)
#define OFF_LUT 53248      // 2049 x 4 (+pad) = 8208
#define ARENA_SZ 61456
#define SLOTF (16 * 68 + 16)   // combine slot: O[16][68] f32 + l[16]

#define GLOBAL_LOAD_LDS16(g, l)                                                  \
  __builtin_amdgcn_global_load_lds((const __attribute__((address_space(1))) void*)(g), \
                                   (__attribute__((address_space(3))) void*)(l), 16, 0, 0)

// raw v_sqrt_f32 (1 ULP) — sqrtf() without fast-math emits the IEEE fixup
// sequence (~10 VALU ops); result only feeds a 2048-bin LUT quantizer.
#define FAST_SQRT(x) __builtin_amdgcn_sqrtf(x)

// ---------------- preprocessing: f32 -> f16 swizzled tiles in ws ----------------
// grid 512 = (b,h,u), u in [0,32): Q-tile u (64 rows), K/V tiles 2u, 2u+1 (32 rows).
__global__ __launch_bounds__(256, 4)
void tisa_preproc(const float* __restrict__ qs, const float* __restrict__ ks,
                  const float* __restrict__ vs, const float* __restrict__ ks_s,
                  _Float16* __restrict__ wsh) {
  __shared__ _Float16 Vl[64 * 72];
  const int t = threadIdx.x;
  const int u = blockIdx.x & 31;
  const int bh = blockIdx.x >> 5;
  const size_t base = ((size_t)(bh >> 3) * L_ + (size_t)u * 64) * (H_ * D_) + (size_t)(bh & 7) * D_;

  // ---- Q: 512 chunks of 8 f32 -> 8 f16, swizzled chunk c^(row&7), scaled by QSC ----
#pragma unroll
  for (int jj = 0; jj < 2; ++jj) {
    int id = t * 2 + jj;              // 0..511
    int row = id >> 3, c = id & 7;
    const float* src = qs + base + (size_t)row * 512 + c * 8;
    f32x4 x0 = ((const f32x4*)src)[0], x1 = ((const f32x4*)src)[1];
    half8 hh;
#pragma unroll
    for (int k = 0; k < 4; ++k) { hh[k] = (_Float16)(x0[k] * QSC); hh[k + 4] = (_Float16)(x1[k] * QSC); }
    *(half8*)&wsh[QOFF + ((size_t)bh * 32 + u) * 4096 + row * 64 + (c ^ (row & 7)) * 8] = hh;
  }
  // ---- K: two 32-row tiles, same chunk swizzle ----
#pragma unroll
  for (int jj = 0; jj < 2; ++jj) {
    int id = t * 2 + jj;
    int tile = id >> 8, row = (id >> 3) & 31, c = id & 7;
    const float* src = ks + base + (size_t)(tile * 32 + row) * 512 + c * 8;
    f32x4 x0 = ((const f32x4*)src)[0], x1 = ((const f32x4*)src)[1];
    half8 hh;
#pragma unroll
    for (int k = 0; k < 4; ++k) { hh[k] = (_Float16)x0[k]; hh[k + 4] = (_Float16)x1[k]; }
    *(half8*)&wsh[KOFF + ((size_t)bh * 64 + u * 2 + tile) * 2048 + row * 64 + (c ^ (row & 7)) * 8] = hh;
  }
  // ---- scaled ks_s coords (h==0 blocks only; 64 keys = 128 floats) ----
  if ((bh & 7) == 0 && t < 32) {
    const int b = bh >> 3;
    const float* src = ks_s + ((size_t)b * L_ + u * 64) * 2 + t * 4;
    float* dst = (float*)(wsh + SOFFH) + ((size_t)b * L_ + u * 64) * 2 + t * 4;
    f32x4 x = *(const f32x4*)src;
    x *= LSCALE;
    *(f32x4*)dst = x;
  }
  // ---- V: stage f16 in LDS, then transposed superrow-swizzled tiles ----
  {
    int key = t >> 2, d0 = (t & 3) * 16;
    const float* src = vs + base + (size_t)key * 512 + d0;
    f32x4 a0 = ((const f32x4*)src)[0], a1 = ((const f32x4*)src)[1];
    f32x4 a2 = ((const f32x4*)src)[2], a3 = ((const f32x4*)src)[3];
    half8 h0, h1;
#pragma unroll
    for (int k = 0; k < 4; ++k) {
      h0[k] = (_Float16)a0[k]; h0[k + 4] = (_Float16)a1[k];
      h1[k] = (_Float16)a2[k]; h1[k + 4] = (_Float16)a3[k];
    }
    *(half8*)&Vl[key * 72 + d0] = h0;
    *(half8*)&Vl[key * 72 + d0 + 8] = h1;
  }
  __syncthreads();
  // superrow s holds d=2s,2s+1; slot c' = (d&1)*4 + (k>>3); stored at c'^(s&7)
#pragma unroll
  for (int jj = 0; jj < 2; ++jj) {
    int id = t * 2 + jj;
    int tile = id >> 8, s = (id >> 3) & 31, cp2 = id & 7;
    int d = 2 * s + (cp2 >> 2), kb = (cp2 & 3) * 8;
    half8 hh;
#pragma unroll
    for (int j = 0; j < 8; ++j) hh[j] = Vl[(tile * 32 + kb + j) * 72 + d];
    *(half8*)&wsh[VOFF + ((size_t)bh * 64 + u * 2 + tile) * 2048 + s * 64 + (cp2 ^ (s & 7)) * 8] = hh;
  }
}

// ---------------- main kernel: 1024 thr = 4 q-slices x 4 K-quarters ----------------
// QK computed TRANSPOSED (S^T = K·Q^T via mfma(kf, qA)): C-layout then gives each
// lane 4 consecutive keys for one q (=l16) -> P scatter is 2x ds_write_b64 and
// k-coords come from ws via broadcast VMEM loads (no LDS coord traffic).
__global__ __launch_bounds__(1024, 8)
void tisa_attn_main(const float* __restrict__ qs_s, const float* __restrict__ ap,
                    const float* __restrict__ bp, const float* __restrict__ cp,
                    const _Float16* __restrict__ wsh, float* __restrict__ out) {
  __shared__ __align__(16) char arena[ARENA_SZ];
  float* LUT = (float*)(arena + OFF_LUT);

  const int t = threadIdx.x;
  const int lane = t & 63;
  const int w = t >> 6;       // 0..15
  const int g = w >> 2;       // K-quarter 0..3
  const int qw = w & 3;       // q-slice 0..3
  const int t2 = t & 255;     // index within group
  const int quad = lane >> 4;
  const int l16 = lane & 15;

  const int qt = blockIdx.x & 31;
  const int bh = blockIdx.x >> 5;
  const int h = bh & 7;
  const int b = bh >> 3;
  const int q0 = qt * 64;

  // ---- LUT (nearest-neighbor, midpoint-sampled): ((bias-8)*log2e) at d=(i+0.5)/LSCALE ----
  {
    float af[F_], nb[F_], cf[F_];
#pragma unroll
    for (int f = 0; f < F_; ++f) {
      af[f] = ap[h * F_ + f];
      nb[f] = -fabsf(bp[h * F_ + f]);
      cf[f] = cp[h * F_ + f];
    }
    for (int i = t; i <= LUTN; i += 1024) {
      float d = ((float)i + 0.5f) * (1.0f / LSCALE);
      float s = 0.f;
#pragma unroll
      for (int f = 0; f < F_; ++f) {
        float e = d - cf[f];
        s += af[f] * __expf(nb[f] * (e * e));
      }
      LUT[i] = (s - 8.0f) * LOG2E;
    }
  }

  // q coords for this lane's S^T column (q = qw*16 + l16), pre-scaled
  const float qx = qs_s[((size_t)b * L_ + q0 + qw * 16 + l16) * 2 + 0] * LSCALE;
  const float qy = qs_s[((size_t)b * L_ + q0 + qw * 16 + l16) * 2 + 1] * LSCALE;

  const _Float16* Qt = wsh + QOFF + ((size_t)bh * 32 + qt) * 4096;
  const _Float16* Kbh = wsh + KOFF + (size_t)bh * 64 * 2048;
  const _Float16* Vbh = wsh + VOFF + (size_t)bh * 64 * 2048;
  const float* wsS = (const float*)(wsh + SOFFH);

  // ---- Q tile (8 KB) -> arena[OFF_K..], waves 0..7 ----
  if (w < 8)
    GLOBAL_LOAD_LDS16(Qt + w * 512 + lane * 8, arena + OFF_K + w * 1024);
  __syncthreads();  // Q staged (+LUT built)

  half8 qA[2];
#pragma unroll
  for (int kb = 0; kb < 2; ++kb)
    qA[kb] = *(const half8*)(arena + OFF_K + (qw * 16 + l16) * 128 +
                             ((kb * 4 + quad) ^ (l16 & 7)) * 16);

  f32x4 oc[4];
#pragma unroll
  for (int df = 0; df < 4; ++df) oc[df] = (f32x4){0.f, 0.f, 0.f, 0.f};
  f32x4 lsacc = (f32x4){0.f, 0.f, 0.f, 0.f};
  half8 onesv;
#pragma unroll
  for (int j = 0; j < 8; ++j) onesv[j] = (_Float16)1.0f;

  const _Float16* ksrc = Kbh + (size_t)(g * 16) * 2048 + t2 * 8;
  const _Float16* vsrc = Vbh + (size_t)(g * 16) * 2048 + t2 * 8;
  // per-lane k-coord base: keys (g*512 + it*32 + nf*16 + quad*4 + r), 2 floats each
  const float* sbase = wsS + ((size_t)b * L_ + g * 512 + quad * 4) * 2;
  char* kdst = arena + OFF_K + g * 4096 + qw * 1024;   // wave-uniform
  char* vdst = arena + OFF_V + g * 4096 + qw * 1024;
  char* Pp = arena + OFF_P + w * 1280 + l16 * 80 + quad * 8;  // b64 write base

  for (int it = 0; it < 16; ++it) {
    // k-coords for this tile (broadcast within quad; VMEM, L2/L1-resident)
    const float* sit = sbase + it * 64;
    f32x4 c01a = *(const f32x4*)(sit);          // nf=0: keys quad*4+0,1
    f32x4 c23a = *(const f32x4*)(sit + 4);      // nf=0: keys quad*4+2,3
    f32x4 c01b = *(const f32x4*)(sit + 32);     // nf=1
    f32x4 c23b = *(const f32x4*)(sit + 36);

    __syncthreads();  // prev iter's frag reads done (iter 0: qA reads done)
    GLOBAL_LOAD_LDS16(ksrc, kdst);
    GLOBAL_LOAD_LDS16(vsrc, vdst);
    ksrc += 2048; vsrc += 2048;
    __syncthreads();  // tiles visible (barrier drains vmcnt)

    // ---- S^T = K·Q^T: 4 MFMA (kf as A-operand, qA as B-operand) ----
    f32x4 acc[2];
#pragma unroll
    for (int nf = 0; nf < 2; ++nf) {
      f32x4 a = (f32x4){0.f, 0.f, 0.f, 0.f};
#pragma unroll
      for (int kb = 0; kb < 2; ++kb) {
        half8 kf = *(const half8*)(arena + OFF_K + g * 4096 + (nf * 16 + l16) * 128 +
                                   ((kb * 4 + quad) ^ (l16 & 7)) * 16);
        a = __builtin_amdgcn_mfma_f32_16x16x32_f16(kf, qA[kb], a, 0, 0, 0);
      }
      acc[nf] = a;  // acc[nf][r] = S[q=l16][key=nf*16+quad*4+r]
    }

    // ---- scores: dist -> LDS-LUT gather -> exp2; P as 2x b64 write (key-contig) ----
#pragma unroll
    for (int nf = 0; nf < 2; ++nf) {
      f32x4 cA = (nf == 0) ? c01a : c01b;
      f32x4 cB = (nf == 0) ? c23a : c23b;
      float kxr[4] = {cA.x, cA.z, cB.x, cB.z};
      float kyr[4] = {cA.y, cA.w, cB.y, cB.w};
      half4 pv;
#pragma unroll
      for (int r = 0; r < 4; ++r) {
        float dx = qx - kxr[r], dy = qy - kyr[r];
        float tt = FAST_SQRT(fmaf(dx, dx, dy * dy));   // = dist * LSCALE
        int ii = (int)tt;
        float p = __builtin_amdgcn_exp2f(acc[nf][r] + LUT[ii]);
        acc[nf][r] = p;
        pv[r] = (_Float16)p;
      }
      *(half4*)(Pp + nf * 32) = pv;   // P[q=l16][key=nf*16+quad*4 .. +3]
    }

    // ---- PV + row-sum via ones-MFMA; same-wave DS ordering, no barrier ----
    half8 pa = *(const half8*)(arena + OFF_P + w * 1280 + l16 * 80 + quad * 16);
    lsacc = __builtin_amdgcn_mfma_f32_16x16x32_f16(pa, onesv, lsacc, 0, 0, 0);
#pragma unroll
    for (int df = 0; df < 4; ++df) {
      half8 vf = *(const half8*)(arena + OFF_V + g * 4096 + (l16 >> 1) * 128 + df * 1024 +
                                 ((((l16 & 1) * 4 + quad) ^ ((l16 >> 1) & 7)) * 16));
      oc[df] = __builtin_amdgcn_mfma_f32_16x16x32_f16(pa, vf, oc[df], 0, 0, 0);
    }
  }

  // ---- combine 4 K-quarters via LDS tree (row sums already reduced by ones-MFMA) ----
  float lred[4];
#pragma unroll
  for (int r = 0; r < 4; ++r) lred[r] = lsacc[r];
  __syncthreads();  // all loop LDS reads done; arena reusable
  float* slots = (float*)arena;
  if (g >= 2) {
    float* sl = slots + ((g - 2) * 4 + qw) * SLOTF;
#pragma unroll
    for (int df = 0; df < 4; ++df)
#pragma unroll
      for (int r = 0; r < 4; ++r)
        sl[(quad * 4 + r) * 68 + df * 16 + l16] = oc[df][r];
    if (l16 == 0) {
#pragma unroll
      for (int r = 0; r < 4; ++r) sl[16 * 68 + quad * 4 + r] = lred[r];
    }
  }
  __syncthreads();
  if (g < 2) {
    float* sl = slots + (g * 4 + qw) * SLOTF;   // g0<-slot(g2), g1<-slot(g3)
#pragma unroll
    for (int df = 0; df < 4; ++df)
#pragma unroll
      for (int r = 0; r < 4; ++r)
        oc[df][r] += sl[(quad * 4 + r) * 68 + df * 16 + l16];
#pragma unroll
    for (int r = 0; r < 4; ++r) lred[r] += sl[16 * 68 + quad * 4 + r];
  }
  if (g == 1) {  // write combined back into same slot (same-wave, in-order)
    float* sl = slots + (4 + qw) * SLOTF;
#pragma unroll
    for (int df = 0; df < 4; ++df)
#pragma unroll
      for (int r = 0; r < 4; ++r)
        sl[(quad * 4 + r) * 68 + df * 16 + l16] = oc[df][r];
    if (l16 == 0) {
#pragma unroll
      for (int r = 0; r < 4; ++r) sl[16 * 68 + quad * 4 + r] = lred[r];
    }
  }
  __syncthreads();
  if (g == 0) {
    float* sl = slots + (4 + qw) * SLOTF;
    float inv_l[4];
#pragma unroll
    for (int r = 0; r < 4; ++r)
      inv_l[r] = 1.f / (lred[r] + sl[16 * 68 + quad * 4 + r]);
#pragma unroll
    for (int df = 0; df < 4; ++df)
#pragma unroll
      for (int r = 0; r < 4; ++r) {
        int qrow = q0 + qw * 16 + quad * 4 + r;
        float v = oc[df][r] + sl[(quad * 4 + r) * 68 + df * 16 + l16];
        out[((size_t)(b * L_ + qrow)) * (H_ * D_) + h * D_ + df * 16 + l16] = v * inv_l[r];
      }
  }
}

// ---------------- fallback (R3 kernel) if ws too small ----------------
#define KSTR 72
#define PH 72
#define FLUTN 512
#define FLSCALE 362.03867f
__global__ __launch_bounds__(512, 4)
void tisa_attn_fallback(const float* __restrict__ qs, const float* __restrict__ ks,
                        const float* __restrict__ vs, const float* __restrict__ qs_s,
                        const float* __restrict__ ks_s, const float* __restrict__ ap,
                        const float* __restrict__ bp, const float* __restrict__ cp,
                        float* __restrict__ out) {
  __shared__ _Float16 Ks[2][64 * KSTR];
  __shared__ _Float16 VT[2][D_ * KSTR];
  __shared__ _Float16 Pf[8][16 * PH];
  __shared__ float kss2[2][64 * 2];
  __shared__ f32x2 LUT2s[FLUTN + 1];
  __shared__ float comb[4][16][64];
  __shared__ float combl[4][16];

  const int t = threadIdx.x;
  const int lane = t & 63;
  const int w = t >> 6;
  const int g = w >> 2;
  const int qw = w & 3;
  const int t2 = t & 255;
  const int quad = lane >> 4;
  const int l16 = lane & 15;
  const int qt = blockIdx.x & 31;
  const int bh = blockIdx.x >> 5;
  const int h = bh & 7;
  const int b = bh >> 3;
  const int q0 = qt * 64;

  float af[F_], nb[F_], cf[F_];
#pragma unroll
  for (int f = 0; f < F_; ++f) {
    af[f] = ap[h * F_ + f];
    nb[f] = -fabsf(bp[h * F_ + f]);
    cf[f] = cp[h * F_ + f];
  }
  for (int i = t; i <= FLUTN; i += 512) {
    float d0 = (float)i * (1.0f / FLSCALE), d1 = (float)(i + 1) * (1.0f / FLSCALE);
    float s0 = 0.f, s1 = 0.f;
#pragma unroll
    for (int f = 0; f < F_; ++f) {
      float e0 = d0 - cf[f], e1 = d1 - cf[f];
      s0 += af[f] * __expf(nb[f] * (e0 * e0));
      s1 += af[f] * __expf(nb[f] * (e1 * e1));
    }
    LUT2s[i] = (f32x2){s0 - 8.0f, s1 - 8.0f};
  }
  float qx[4], qy[4];
#pragma unroll
  for (int r = 0; r < 4; ++r) {
    int qrow = q0 + qw * 16 + quad * 4 + r;
    qx[r] = qs_s[(b * L_ + qrow) * S_ + 0];
    qy[r] = qs_s[(b * L_ + qrow) * S_ + 1];
  }
  if (t < 256) {
    const int row = t >> 2, dc = (t & 3) * 16;
    const float* src = qs + (((size_t)(b * L_ + q0 + row)) * H_ + h) * D_ + dc;
    const f32x4* s4 = (const f32x4*)src;
    f32x4 v0 = s4[0], v1 = s4[1], v2 = s4[2], v3 = s4[3];
    half8 w0, w1;
#pragma unroll
    for (int u = 0; u < 4; ++u) {
      w0[u] = (_Float16)(v0[u] * 0.125f); w0[u + 4] = (_Float16)(v1[u] * 0.125f);
      w1[u] = (_Float16)(v2[u] * 0.125f); w1[u + 4] = (_Float16)(v3[u] * 0.125f);
    }
    *(half8*)&Ks[0][row * KSTR + dc] = w0;
    *(half8*)&Ks[0][row * KSTR + dc + 8] = w1;
  }
  __syncthreads();
  half8 qA[2];
#pragma unroll
  for (int kb = 0; kb < 2; ++kb)
    qA[kb] = *(const half8*)&Ks[0][(qw * 16 + l16) * KSTR + kb * 32 + quad * 8];
  f32x4 oc[4];
#pragma unroll
  for (int df = 0; df < 4; ++df) oc[df] = (f32x4){0.f, 0.f, 0.f, 0.f};
  float l_r[4] = {0.f, 0.f, 0.f, 0.f};

  for (int it = 0; it < 16; ++it) {
    const int k0 = (g * 16 + it) * 64;
    __syncthreads();
    {
      const int row = t2 >> 2, dc = (t2 & 3) * 16;
      const float* src = ks + (((size_t)(b * L_ + k0 + row)) * H_ + h) * D_ + dc;
      const f32x4* s4 = (const f32x4*)src;
      f32x4 v0 = s4[0], v1 = s4[1], v2 = s4[2], v3 = s4[3];
      half8 w0, w1;
#pragma unroll
      for (int u = 0; u < 4; ++u) {
        w0[u] = (_Float16)v0[u]; w0[u + 4] = (_Float16)v1[u];
        w1[u] = (_Float16)v2[u]; w1[u + 4] = (_Float16)v3[u];
      }
      *(half8*)&Ks[g][row * KSTR + dc] = w0;
      *(half8*)&Ks[g][row * KSTR + dc + 8] = w1;
    }
    {
      const int kk = (t2 & 31) * 2, dg = (t2 >> 5) * 8;
      const float* s0 = vs + (((size_t)(b * L_ + k0 + kk)) * H_ + h) * D_ + dg;
      const float* s1 = s0 + H_ * D_;
      f32x4 a0 = ((const f32x4*)s0)[0], a1 = ((const f32x4*)s0)[1];
      f32x4 b0 = ((const f32x4*)s1)[0], b1 = ((const f32x4*)s1)[1];
#pragma unroll
      for (int u = 0; u < 4; ++u) {
        half2v p0 = {(_Float16)a0[u], (_Float16)b0[u]};
        *(half2v*)&VT[g][(dg + u) * KSTR + kk] = p0;
        half2v p1 = {(_Float16)a1[u], (_Float16)b1[u]};
        *(half2v*)&VT[g][(dg + 4 + u) * KSTR + kk] = p1;
      }
    }
    if (t2 < 128) kss2[g][t2] = ks_s[((size_t)(b * L_) + k0 + (t2 >> 1)) * S_ + (t2 & 1)];
    __syncthreads();
    f32x4 acc[4];
#pragma unroll
    for (int nf = 0; nf < 4; ++nf) {
      f32x4 a = (f32x4){0.f, 0.f, 0.f, 0.f};
#pragma unroll
      for (int kb = 0; kb < 2; ++kb) {
        half8 kf = *(const half8*)&Ks[g][(nf * 16 + l16) * KSTR + kb * 32 + quad * 8];
        a = __builtin_amdgcn_mfma_f32_16x16x32_f16(qA[kb], kf, a, 0, 0, 0);
      }
      acc[nf] = a;
    }
#pragma unroll
    for (int nf = 0; nf < 4; ++nf) {
      float kx = kss2[g][(nf * 16 + l16) * 2 + 0];
      float ky = kss2[g][(nf * 16 + l16) * 2 + 1];
#pragma unroll
      for (int r = 0; r < 4; ++r) {
        float dx = qx[r] - kx, dy = qy[r] - ky;
        float dist = FAST_SQRT(fmaf(dx, dx, dy * dy));
        float tt = dist * FLSCALE;
        int ii = (int)tt;
        float fr = tt - (float)ii;
        f32x2 lh = LUT2s[ii];
        float p = __expf(acc[nf][r] + fmaf(fr, lh.y - lh.x, lh.x));
        acc[nf][r] = p;
      }
    }
#pragma unroll
    for (int r = 0; r < 4; ++r)
      l_r[r] += (acc[0][r] + acc[1][r]) + (acc[2][r] + acc[3][r]);
#pragma unroll
    for (int nf = 0; nf < 4; ++nf)
#pragma unroll
      for (int r = 0; r < 4; ++r)
        Pf[w][(quad * 4 + r) * PH + nf * 16 + l16] = (_Float16)acc[nf][r];
#pragma unroll
    for (int kb = 0; kb < 2; ++kb) {
      half8 pa = *(const half8*)&Pf[w][l16 * PH + kb * 32 + quad * 8];
#pragma unroll
      for (int df = 0; df < 4; ++df) {
        half8 vf = *(const half8*)&VT[g][(df * 16 + l16) * KSTR + kb * 32 + quad * 8];
        oc[df] = __builtin_amdgcn_mfma_f32_16x16x32_f16(pa, vf, oc[df], 0, 0, 0);
      }
    }
  }
  __syncthreads();
  float lred[4];
#pragma unroll
  for (int r = 0; r < 4; ++r) {
    float s = l_r[r];
    s += __shfl_xor(s, 1); s += __shfl_xor(s, 2);
    s += __shfl_xor(s, 4); s += __shfl_xor(s, 8);
    lred[r] = s;
  }
  if (g == 1) {
#pragma unroll
    for (int df = 0; df < 4; ++df)
#pragma unroll
      for (int r = 0; r < 4; ++r)
        comb[qw][quad * 4 + r][df * 16 + l16] = oc[df][r];
    if (l16 == 0) {
#pragma unroll
      for (int r = 0; r < 4; ++r) combl[qw][quad * 4 + r] = lred[r];
    }
  }
  __syncthreads();
  if (g == 0) {
    float inv_l[4];
#pragma unroll
    for (int r = 0; r < 4; ++r)
      inv_l[r] = 1.f / (lred[r] + combl[qw][quad * 4 + r]);
#pragma unroll
    for (int df = 0; df < 4; ++df)
#pragma unroll
      for (int r = 0; r < 4; ++r) {
        int qrow = q0 + qw * 16 + quad * 4 + r;
        float v = oc[df][r] + comb[qw][quad * 4 + r][df * 16 + l16];
        out[(((size_t)(b * L_ + qrow)) * H_ + h) * D_ + df * 16 + l16] = v * inv_l[r];
      }
  }
}

extern "C" void kernel_launch(void* const* d_in, const int* in_sizes, int n_in,
                              void* d_out, int out_size, void* d_ws, size_t ws_size,
                              hipStream_t stream) {
  const float* qs = (const float*)d_in[0];
  const float* ks = (const float*)d_in[1];
  const float* vs = (const float*)d_in[2];
  const float* qs_s = (const float*)d_in[3];
  const float* ks_s = (const float*)d_in[4];
  const float* ap = (const float*)d_in[5];
  const float* bp = (const float*)d_in[6];
  const float* cp = (const float*)d_in[7];
  float* out = (float*)d_out;

  if (ws_size >= (size_t)WS_NEED) {
    _Float16* wsh = (_Float16*)d_ws;
    tisa_preproc<<<dim3(512), dim3(256), 0, stream>>>(qs, ks, vs, ks_s, wsh);
    tisa_attn_main<<<dim3(512), dim3(1024), 0, stream>>>(qs_s, ap, bp, cp, wsh, out);
  } else {
    tisa_attn_fallback<<<dim3(512), dim3(512), 0, stream>>>(qs, ks, vs, qs_s, ks_s, ap, bp, cp, out);
  }
}

// Round 10
// 133.744 us; speedup vs baseline: 1.2329x; 1.1543x over previous
//
#include <hip/hip_runtime.h>
#include <cmath>

typedef _Float16 half8 __attribute__((ext_vector_type(8)));
typedef _Float16 half4 __attribute__((ext_vector_type(4)));
typedef _Float16 half2v __attribute__((ext_vector_type(2)));
typedef float f32x4 __attribute__((ext_vector_type(4)));
typedef float f32x2 __attribute__((ext_vector_type(2)));

#define B_ 2
#define L_ 2048
#define H_ 8
#define D_ 64
#define S_ 2
#define F_ 5
#define LUTN 2048
#define LSCALE 1448.1547f          // LUTN / sqrt(2)
#define LOG2E 1.44269504f
#define QSC (0.125f * LOG2E)       // folded into Q at preprocess

// ws layout: Q tiles (64x64 f16, swizzled), K tiles (32x64 f16, swizzled),
// VT tiles (superrow-swizzled f16, KEY-PERMUTED for register-resident P),
// then pre-scaled ks_s coords (f32).
#define QOFF 0            // halfs
#define KOFF 2097152      // halfs
#define VOFF 4194304      // halfs
#define SOFFH 6291456     // halfs -> (float*)(wsh + SOFFH)
#define WS_NEED 12615680  // bytes

// main-kernel LDS arena offsets (bytes). No P region: P lives in registers.
#define OFF_K 0            // 4 groups x 4096 (Q tile overlays groups 0-1 pre-loop)
#define OFF_V 16384        // 4 groups x 4096
#define OFF_LUT 32768      // 2049 x 4 (+pad)
#define ARENA_SZ 40976
#define SLOTF (16 * 68 + 16)   // combine slot: O[16][68] f32 + l[16]

#define GLOBAL_LOAD_LDS16(g, l)                                                  \
  __builtin_amdgcn_global_load_lds((const __attribute__((address_space(1))) void*)(g), \
                                   (__attribute__((address_space(3))) void*)(l), 16, 0, 0)

// raw v_sqrt_f32 (1 ULP) — sqrtf() without fast-math emits the IEEE fixup
// sequence (~10 VALU ops); result only feeds a 2048-bin LUT quantizer.
#define FAST_SQRT(x) __builtin_amdgcn_sqrtf(x)

// ---------------- preprocessing: f32 -> f16 swizzled tiles in ws ----------------
// grid 512 = (b,h,u), u in [0,32): Q-tile u (64 rows), K/V tiles 2u, 2u+1 (32 rows).
__global__ __launch_bounds__(256, 4)
void tisa_preproc(const float* __restrict__ qs, const float* __restrict__ ks,
                  const float* __restrict__ vs, const float* __restrict__ ks_s,
                  _Float16* __restrict__ wsh) {
  __shared__ _Float16 Vl[64 * 72];
  const int t = threadIdx.x;
  const int u = blockIdx.x & 31;
  const int bh = blockIdx.x >> 5;
  const size_t base = ((size_t)(bh >> 3) * L_ + (size_t)u * 64) * (H_ * D_) + (size_t)(bh & 7) * D_;

  // ---- Q: 512 chunks of 8 f32 -> 8 f16, swizzled chunk c^(row&7), scaled by QSC ----
#pragma unroll
  for (int jj = 0; jj < 2; ++jj) {
    int id = t * 2 + jj;              // 0..511
    int row = id >> 3, c = id & 7;
    const float* src = qs + base + (size_t)row * 512 + c * 8;
    f32x4 x0 = ((const f32x4*)src)[0], x1 = ((const f32x4*)src)[1];
    half8 hh;
#pragma unroll
    for (int k = 0; k < 4; ++k) { hh[k] = (_Float16)(x0[k] * QSC); hh[k + 4] = (_Float16)(x1[k] * QSC); }
    *(half8*)&wsh[QOFF + ((size_t)bh * 32 + u) * 4096 + row * 64 + (c ^ (row & 7)) * 8] = hh;
  }
  // ---- K: two 32-row tiles, same chunk swizzle ----
#pragma unroll
  for (int jj = 0; jj < 2; ++jj) {
    int id = t * 2 + jj;
    int tile = id >> 8, row = (id >> 3) & 31, c = id & 7;
    const float* src = ks + base + (size_t)(tile * 32 + row) * 512 + c * 8;
    f32x4 x0 = ((const f32x4*)src)[0], x1 = ((const f32x4*)src)[1];
    half8 hh;
#pragma unroll
    for (int k = 0; k < 4; ++k) { hh[k] = (_Float16)x0[k]; hh[k + 4] = (_Float16)x1[k]; }
    *(half8*)&wsh[KOFF + ((size_t)bh * 64 + u * 2 + tile) * 2048 + row * 64 + (c ^ (row & 7)) * 8] = hh;
  }
  // ---- scaled ks_s coords (h==0 blocks only; 64 keys = 128 floats) ----
  if ((bh & 7) == 0 && t < 32) {
    const int b = bh >> 3;
    const float* src = ks_s + ((size_t)b * L_ + u * 64) * 2 + t * 4;
    float* dst = (float*)(wsh + SOFFH) + ((size_t)b * L_ + u * 64) * 2 + t * 4;
    f32x4 x = *(const f32x4*)src;
    x *= LSCALE;
    *(f32x4*)dst = x;
  }
  // ---- V: stage f16 in LDS, then transposed superrow-swizzled tiles,
  //      keys PERMUTED to key' space: key' = quad*8+nf*4+r for key = nf*16+quad*4+r
  //      => orig(key') = ((key'>>2)&1)*16 + (key'>>3)*4 + (key'&3).
  //      This makes the S^T-MFMA C registers directly usable as the PV A-fragment.
  {
    int key = t >> 2, d0 = (t & 3) * 16;
    const float* src = vs + base + (size_t)key * 512 + d0;
    f32x4 a0 = ((const f32x4*)src)[0], a1 = ((const f32x4*)src)[1];
    f32x4 a2 = ((const f32x4*)src)[2], a3 = ((const f32x4*)src)[3];
    half8 h0, h1;
#pragma unroll
    for (int k = 0; k < 4; ++k) {
      h0[k] = (_Float16)a0[k]; h0[k + 4] = (_Float16)a1[k];
      h1[k] = (_Float16)a2[k]; h1[k + 4] = (_Float16)a3[k];
    }
    *(half8*)&Vl[key * 72 + d0] = h0;
    *(half8*)&Vl[key * 72 + d0 + 8] = h1;
  }
  __syncthreads();
  // superrow s holds d=2s,2s+1; slot c' = (d&1)*4 + (key'>>3); stored at c'^(s&7)
#pragma unroll
  for (int jj = 0; jj < 2; ++jj) {
    int id = t * 2 + jj;
    int tile = id >> 8, s = (id >> 3) & 31, cp2 = id & 7;
    int d = 2 * s + (cp2 >> 2), kb = (cp2 & 3) * 8;
    half8 hh;
#pragma unroll
    for (int j = 0; j < 8; ++j) {
      int kpj = kb + j;  // key' index
      int orig = ((kpj >> 2) & 1) * 16 + (kpj >> 3) * 4 + (kpj & 3);
      hh[j] = Vl[(tile * 32 + orig) * 72 + d];
    }
    *(half8*)&wsh[VOFF + ((size_t)bh * 64 + u * 2 + tile) * 2048 + s * 64 + (cp2 ^ (s & 7)) * 8] = hh;
  }
}

// ---------------- main kernel: 1024 thr = 4 q-slices x 4 K-quarters ----------------
// S^T = K·Q^T via mfma(kf, qA). With the key' permutation baked into V, the
// score registers ARE the PV A-fragment: P never touches LDS.
__global__ __launch_bounds__(1024, 8)
void tisa_attn_main(const float* __restrict__ qs_s, const float* __restrict__ ap,
                    const float* __restrict__ bp, const float* __restrict__ cp,
                    const _Float16* __restrict__ wsh, float* __restrict__ out) {
  __shared__ __align__(16) char arena[ARENA_SZ];
  float* LUT = (float*)(arena + OFF_LUT);

  const int t = threadIdx.x;
  const int lane = t & 63;
  const int w = t >> 6;       // 0..15
  const int g = w >> 2;       // K-quarter 0..3
  const int qw = w & 3;       // q-slice 0..3
  const int t2 = t & 255;     // index within group
  const int quad = lane >> 4;
  const int l16 = lane & 15;

  const int qt = blockIdx.x & 31;
  const int bh = blockIdx.x >> 5;
  const int h = bh & 7;
  const int b = bh >> 3;
  const int q0 = qt * 64;

  // ---- LUT (nearest-neighbor, midpoint-sampled): ((bias-8)*log2e) at d=(i+0.5)/LSCALE ----
  {
    float af[F_], nb[F_], cf[F_];
#pragma unroll
    for (int f = 0; f < F_; ++f) {
      af[f] = ap[h * F_ + f];
      nb[f] = -fabsf(bp[h * F_ + f]);
      cf[f] = cp[h * F_ + f];
    }
    for (int i = t; i <= LUTN; i += 1024) {
      float d = ((float)i + 0.5f) * (1.0f / LSCALE);
      float s = 0.f;
#pragma unroll
      for (int f = 0; f < F_; ++f) {
        float e = d - cf[f];
        s += af[f] * __expf(nb[f] * (e * e));
      }
      LUT[i] = (s - 8.0f) * LOG2E;
    }
  }

  // q coords for this lane's S^T column (q = qw*16 + l16), pre-scaled
  const float qx = qs_s[((size_t)b * L_ + q0 + qw * 16 + l16) * 2 + 0] * LSCALE;
  const float qy = qs_s[((size_t)b * L_ + q0 + qw * 16 + l16) * 2 + 1] * LSCALE;

  const _Float16* Qt = wsh + QOFF + ((size_t)bh * 32 + qt) * 4096;
  const _Float16* Kbh = wsh + KOFF + (size_t)bh * 64 * 2048;
  const _Float16* Vbh = wsh + VOFF + (size_t)bh * 64 * 2048;
  const float* wsS = (const float*)(wsh + SOFFH);

  // ---- Q tile (8 KB) -> arena[OFF_K..], waves 0..7 ----
  if (w < 8)
    GLOBAL_LOAD_LDS16(Qt + w * 512 + lane * 8, arena + OFF_K + w * 1024);
  __syncthreads();  // Q staged (+LUT built)

  half8 qA[2];
#pragma unroll
  for (int kb = 0; kb < 2; ++kb)
    qA[kb] = *(const half8*)(arena + OFF_K + (qw * 16 + l16) * 128 +
                             ((kb * 4 + quad) ^ (l16 & 7)) * 16);

  f32x4 oc[4];
#pragma unroll
  for (int df = 0; df < 4; ++df) oc[df] = (f32x4){0.f, 0.f, 0.f, 0.f};
  f32x4 lsacc = (f32x4){0.f, 0.f, 0.f, 0.f};
  half8 onesv;
#pragma unroll
  for (int j = 0; j < 8; ++j) onesv[j] = (_Float16)1.0f;

  const _Float16* ksrc = Kbh + (size_t)(g * 16) * 2048 + t2 * 8;
  const _Float16* vsrc = Vbh + (size_t)(g * 16) * 2048 + t2 * 8;
  // per-lane k-coord base: keys (g*512 + it*32 + nf*16 + quad*4 + r), 2 floats each
  const float* sbase = wsS + ((size_t)b * L_ + g * 512 + quad * 4) * 2;
  char* kdst = arena + OFF_K + g * 4096 + qw * 1024;   // wave-uniform
  char* vdst = arena + OFF_V + g * 4096 + qw * 1024;

  for (int it = 0; it < 16; ++it) {
    __syncthreads();  // prev iter's frag reads done (iter 0: qA reads done)
    GLOBAL_LOAD_LDS16(ksrc, kdst);
    GLOBAL_LOAD_LDS16(vsrc, vdst);
    ksrc += 2048; vsrc += 2048;
    __syncthreads();  // tiles visible (barrier drains vmcnt)

    // k-coords issued AFTER the barrier: latency hidden by QK phase + 8 waves/SIMD,
    // never drained at a barrier (R9's regression).
    const float* sit = sbase + it * 64;
    f32x4 c01a = *(const f32x4*)(sit);          // nf=0: keys quad*4+0,1
    f32x4 c23a = *(const f32x4*)(sit + 4);      // nf=0: keys quad*4+2,3
    f32x4 c01b = *(const f32x4*)(sit + 32);     // nf=1
    f32x4 c23b = *(const f32x4*)(sit + 36);

    // ---- S^T = K·Q^T: 4 MFMA (kf as A-operand, qA as B-operand) ----
    f32x4 acc[2];
#pragma unroll
    for (int nf = 0; nf < 2; ++nf) {
      f32x4 a = (f32x4){0.f, 0.f, 0.f, 0.f};
#pragma unroll
      for (int kb = 0; kb < 2; ++kb) {
        half8 kf = *(const half8*)(arena + OFF_K + g * 4096 + (nf * 16 + l16) * 128 +
                                   ((kb * 4 + quad) ^ (l16 & 7)) * 16);
        a = __builtin_amdgcn_mfma_f32_16x16x32_f16(kf, qA[kb], a, 0, 0, 0);
      }
      acc[nf] = a;  // acc[nf][r] = S[q=qw*16+l16][key=nf*16+quad*4+r] = P[q][key'=quad*8+nf*4+r]
    }

    // ---- scores: dist -> LDS-LUT gather -> exp2; P packed in registers (key' order) ----
    half8 pw;
#pragma unroll
    for (int nf = 0; nf < 2; ++nf) {
      f32x4 cA = (nf == 0) ? c01a : c01b;
      f32x4 cB = (nf == 0) ? c23a : c23b;
      float kxr[4] = {cA.x, cA.z, cB.x, cB.z};
      float kyr[4] = {cA.y, cA.w, cB.y, cB.w};
#pragma unroll
      for (int r = 0; r < 4; ++r) {
        float dx = qx - kxr[r], dy = qy - kyr[r];
        float tt = FAST_SQRT(fmaf(dx, dx, dy * dy));   // = dist * LSCALE
        int ii = (int)tt;
        float p = __builtin_amdgcn_exp2f(acc[nf][r] + LUT[ii]);
        pw[nf * 4 + r] = (_Float16)p;   // A-frag element k=quad*8+nf*4+r
      }
    }

    // ---- PV + row-sum via ones-MFMA; pw IS the A-fragment (no LDS round-trip) ----
    lsacc = __builtin_amdgcn_mfma_f32_16x16x32_f16(pw, onesv, lsacc, 0, 0, 0);
#pragma unroll
    for (int df = 0; df < 4; ++df) {
      half8 vf = *(const half8*)(arena + OFF_V + g * 4096 + (l16 >> 1) * 128 + df * 1024 +
                                 ((((l16 & 1) * 4 + quad) ^ ((l16 >> 1) & 7)) * 16));
      oc[df] = __builtin_amdgcn_mfma_f32_16x16x32_f16(pw, vf, oc[df], 0, 0, 0);
    }
  }

  // ---- combine 4 K-quarters via LDS tree (row sums already reduced by ones-MFMA) ----
  float lred[4];
#pragma unroll
  for (int r = 0; r < 4; ++r) lred[r] = lsacc[r];
  __syncthreads();  // all loop LDS reads done; arena reusable
  float* slots = (float*)arena;
  if (g >= 2) {
    float* sl = slots + ((g - 2) * 4 + qw) * SLOTF;
#pragma unroll
    for (int df = 0; df < 4; ++df)
#pragma unroll
      for (int r = 0; r < 4; ++r)
        sl[(quad * 4 + r) * 68 + df * 16 + l16] = oc[df][r];
    if (l16 == 0) {
#pragma unroll
      for (int r = 0; r < 4; ++r) sl[16 * 68 + quad * 4 + r] = lred[r];
    }
  }
  __syncthreads();
  if (g < 2) {
    float* sl = slots + (g * 4 + qw) * SLOTF;   // g0<-slot(g2), g1<-slot(g3)
#pragma unroll
    for (int df = 0; df < 4; ++df)
#pragma unroll
      for (int r = 0; r < 4; ++r)
        oc[df][r] += sl[(quad * 4 + r) * 68 + df * 16 + l16];
#pragma unroll
    for (int r = 0; r < 4; ++r) lred[r] += sl[16 * 68 + quad * 4 + r];
  }
  if (g == 1) {  // write combined back into same slot (same-wave, in-order)
    float* sl = slots + (4 + qw) * SLOTF;
#pragma unroll
    for (int df = 0; df < 4; ++df)
#pragma unroll
      for (int r = 0; r < 4; ++r)
        sl[(quad * 4 + r) * 68 + df * 16 + l16] = oc[df][r];
    if (l16 == 0) {
#pragma unroll
      for (int r = 0; r < 4; ++r) sl[16 * 68 + quad * 4 + r] = lred[r];
    }
  }
  __syncthreads();
  if (g == 0) {
    float* sl = slots + (4 + qw) * SLOTF;
    float inv_l[4];
#pragma unroll
    for (int r = 0; r < 4; ++r)
      inv_l[r] = 1.f / (lred[r] + sl[16 * 68 + quad * 4 + r]);
#pragma unroll
    for (int df = 0; df < 4; ++df)
#pragma unroll
      for (int r = 0; r < 4; ++r) {
        int qrow = q0 + qw * 16 + quad * 4 + r;
        float v = oc[df][r] + sl[(quad * 4 + r) * 68 + df * 16 + l16];
        out[((size_t)(b * L_ + qrow)) * (H_ * D_) + h * D_ + df * 16 + l16] = v * inv_l[r];
      }
  }
}

// ---------------- fallback (R3 kernel) if ws too small ----------------
#define KSTR 72
#define PH 72
#define FLUTN 512
#define FLSCALE 362.03867f
__global__ __launch_bounds__(512, 4)
void tisa_attn_fallback(const float* __restrict__ qs, const float* __restrict__ ks,
                        const float* __restrict__ vs, const float* __restrict__ qs_s,
                        const float* __restrict__ ks_s, const float* __restrict__ ap,
                        const float* __restrict__ bp, const float* __restrict__ cp,
                        float* __restrict__ out) {
  __shared__ _Float16 Ks[2][64 * KSTR];
  __shared__ _Float16 VT[2][D_ * KSTR];
  __shared__ _Float16 Pf[8][16 * PH];
  __shared__ float kss2[2][64 * 2];
  __shared__ f32x2 LUT2s[FLUTN + 1];
  __shared__ float comb[4][16][64];
  __shared__ float combl[4][16];

  const int t = threadIdx.x;
  const int lane = t & 63;
  const int w = t >> 6;
  const int g = w >> 2;
  const int qw = w & 3;
  const int t2 = t & 255;
  const int quad = lane >> 4;
  const int l16 = lane & 15;
  const int qt = blockIdx.x & 31;
  const int bh = blockIdx.x >> 5;
  const int h = bh & 7;
  const int b = bh >> 3;
  const int q0 = qt * 64;

  float af[F_], nb[F_], cf[F_];
#pragma unroll
  for (int f = 0; f < F_; ++f) {
    af[f] = ap[h * F_ + f];
    nb[f] = -fabsf(bp[h * F_ + f]);
    cf[f] = cp[h * F_ + f];
  }
  for (int i = t; i <= FLUTN; i += 512) {
    float d0 = (float)i * (1.0f / FLSCALE), d1 = (float)(i + 1) * (1.0f / FLSCALE);
    float s0 = 0.f, s1 = 0.f;
#pragma unroll
    for (int f = 0; f < F_; ++f) {
      float e0 = d0 - cf[f], e1 = d1 - cf[f];
      s0 += af[f] * __expf(nb[f] * (e0 * e0));
      s1 += af[f] * __expf(nb[f] * (e1 * e1));
    }
    LUT2s[i] = (f32x2){s0 - 8.0f, s1 - 8.0f};
  }
  float qx[4], qy[4];
#pragma unroll
  for (int r = 0; r < 4; ++r) {
    int qrow = q0 + qw * 16 + quad * 4 + r;
    qx[r] = qs_s[(b * L_ + qrow) * S_ + 0];
    qy[r] = qs_s[(b * L_ + qrow) * S_ + 1];
  }
  if (t < 256) {
    const int row = t >> 2, dc = (t & 3) * 16;
    const float* src = qs + (((size_t)(b * L_ + q0 + row)) * H_ + h) * D_ + dc;
    const f32x4* s4 = (const f32x4*)src;
    f32x4 v0 = s4[0], v1 = s4[1], v2 = s4[2], v3 = s4[3];
    half8 w0, w1;
#pragma unroll
    for (int u = 0; u < 4; ++u) {
      w0[u] = (_Float16)(v0[u] * 0.125f); w0[u + 4] = (_Float16)(v1[u] * 0.125f);
      w1[u] = (_Float16)(v2[u] * 0.125f); w1[u + 4] = (_Float16)(v3[u] * 0.125f);
    }
    *(half8*)&Ks[0][row * KSTR + dc] = w0;
    *(half8*)&Ks[0][row * KSTR + dc + 8] = w1;
  }
  __syncthreads();
  half8 qA[2];
#pragma unroll
  for (int kb = 0; kb < 2; ++kb)
    qA[kb] = *(const half8*)&Ks[0][(qw * 16 + l16) * KSTR + kb * 32 + quad * 8];
  f32x4 oc[4];
#pragma unroll
  for (int df = 0; df < 4; ++df) oc[df] = (f32x4){0.f, 0.f, 0.f, 0.f};
  float l_r[4] = {0.f, 0.f, 0.f, 0.f};

  for (int it = 0; it < 16; ++it) {
    const int k0 = (g * 16 + it) * 64;
    __syncthreads();
    {
      const int row = t2 >> 2, dc = (t2 & 3) * 16;
      const float* src = ks + (((size_t)(b * L_ + k0 + row)) * H_ + h) * D_ + dc;
      const f32x4* s4 = (const f32x4*)src;
      f32x4 v0 = s4[0], v1 = s4[1], v2 = s4[2], v3 = s4[3];
      half8 w0, w1;
#pragma unroll
      for (int u = 0; u < 4; ++u) {
        w0[u] = (_Float16)v0[u]; w0[u + 4] = (_Float16)v1[u];
        w1[u] = (_Float16)v2[u]; w1[u + 4] = (_Float16)v3[u];
      }
      *(half8*)&Ks[g][row * KSTR + dc] = w0;
      *(half8*)&Ks[g][row * KSTR + dc + 8] = w1;
    }
    {
      const int kk = (t2 & 31) * 2, dg = (t2 >> 5) * 8;
      const float* s0 = vs + (((size_t)(b * L_ + k0 + kk)) * H_ + h) * D_ + dg;
      const float* s1 = s0 + H_ * D_;
      f32x4 a0 = ((const f32x4*)s0)[0], a1 = ((const f32x4*)s0)[1];
      f32x4 b0 = ((const f32x4*)s1)[0], b1 = ((const f32x4*)s1)[1];
#pragma unroll
      for (int u = 0; u < 4; ++u) {
        half2v p0 = {(_Float16)a0[u], (_Float16)b0[u]};
        *(half2v*)&VT[g][(dg + u) * KSTR + kk] = p0;
        half2v p1 = {(_Float16)a1[u], (_Float16)b1[u]};
        *(half2v*)&VT[g][(dg + 4 + u) * KSTR + kk] = p1;
      }
    }
    if (t2 < 128) kss2[g][t2] = ks_s[((size_t)(b * L_) + k0 + (t2 >> 1)) * S_ + (t2 & 1)];
    __syncthreads();
    f32x4 acc[4];
#pragma unroll
    for (int nf = 0; nf < 4; ++nf) {
      f32x4 a = (f32x4){0.f, 0.f, 0.f, 0.f};
#pragma unroll
      for (int kb = 0; kb < 2; ++kb) {
        half8 kf = *(const half8*)&Ks[g][(nf * 16 + l16) * KSTR + kb * 32 + quad * 8];
        a = __builtin_amdgcn_mfma_f32_16x16x32_f16(qA[kb], kf, a, 0, 0, 0);
      }
      acc[nf] = a;
    }
#pragma unroll
    for (int nf = 0; nf < 4; ++nf) {
      float kx = kss2[g][(nf * 16 + l16) * 2 + 0];
      float ky = kss2[g][(nf * 16 + l16) * 2 + 1];
#pragma unroll
      for (int r = 0; r < 4; ++r) {
        float dx = qx[r] - kx, dy = qy[r] - ky;
        float dist = FAST_SQRT(fmaf(dx, dx, dy * dy));
        float tt = dist * FLSCALE;
        int ii = (int)tt;
        float fr = tt - (float)ii;
        f32x2 lh = LUT2s[ii];
        float p = __expf(acc[nf][r] + fmaf(fr, lh.y - lh.x, lh.x));
        acc[nf][r] = p;
      }
    }
#pragma unroll
    for (int r = 0; r < 4; ++r)
      l_r[r] += (acc[0][r] + acc[1][r]) + (acc[2][r] + acc[3][r]);
#pragma unroll
    for (int nf = 0; nf < 4; ++nf)
#pragma unroll
      for (int r = 0; r < 4; ++r)
        Pf[w][(quad * 4 + r) * PH + nf * 16 + l16] = (_Float16)acc[nf][r];
#pragma unroll
    for (int kb = 0; kb < 2; ++kb) {
      half8 pa = *(const half8*)&Pf[w][l16 * PH + kb * 32 + quad * 8];
#pragma unroll
      for (int df = 0; df < 4; ++df) {
        half8 vf = *(const half8*)&VT[g][(df * 16 + l16) * KSTR + kb * 32 + quad * 8];
        oc[df] = __builtin_amdgcn_mfma_f32_16x16x32_f16(pa, vf, oc[df], 0, 0, 0);
      }
    }
  }
  __syncthreads();
  float lred[4];
#pragma unroll
  for (int r = 0; r < 4; ++r) {
    float s = l_r[r];
    s += __shfl_xor(s, 1); s += __shfl_xor(s, 2);
    s += __shfl_xor(s, 4); s += __shfl_xor(s, 8);
    lred[r] = s;
  }
  if (g == 1) {
#pragma unroll
    for (int df = 0; df < 4; ++df)
#pragma unroll
      for (int r = 0; r < 4; ++r)
        comb[qw][quad * 4 + r][df * 16 + l16] = oc[df][r];
    if (l16 == 0) {
#pragma unroll
      for (int r = 0; r < 4; ++r) combl[qw][quad * 4 + r] = lred[r];
    }
  }
  __syncthreads();
  if (g == 0) {
    float inv_l[4];
#pragma unroll
    for (int r = 0; r < 4; ++r)
      inv_l[r] = 1.f / (lred[r] + combl[qw][quad * 4 + r]);
#pragma unroll
    for (int df = 0; df < 4; ++df)
#pragma unroll
      for (int r = 0; r < 4; ++r) {
        int qrow = q0 + qw * 16 + quad * 4 + r;
        float v = oc[df][r] + combl[qw][quad * 4 + r] * 0.f + comb[qw][quad * 4 + r][df * 16 + l16];
        out[(((size_t)(b * L_ + qrow)) * H_ + h) * D_ + df * 16 + l16] = v * inv_l[r];
      }
  }
}

extern "C" void kernel_launch(void* const* d_in, const int* in_sizes, int n_in,
                              void* d_out, int out_size, void* d_ws, size_t ws_size,
                              hipStream_t stream) {
  const float* qs = (const float*)d_in[0];
  const float* ks = (const float*)d_in[1];
  const float* vs = (const float*)d_in[2];
  const float* qs_s = (const float*)d_in[3];
  const float* ks_s = (const float*)d_in[4];
  const float* ap = (const float*)d_in[5];
  const float* bp = (const float*)d_in[6];
  const float* cp = (const float*)d_in[7];
  float* out = (float*)d_out;

  if (ws_size >= (size_t)WS_NEED) {
    _Float16* wsh = (_Float16*)d_ws;
    tisa_preproc<<<dim3(512), dim3(256), 0, stream>>>(qs, ks, vs, ks_s, wsh);
    tisa_attn_main<<<dim3(512), dim3(1024), 0, stream>>>(qs_s, ap, bp, cp, wsh, out);
  } else {
    tisa_attn_fallback<<<dim3(512), dim3(512), 0, stream>>>(qs, ks, vs, qs_s, ks_s, ap, bp, cp, out);
  }
}